// Round 1
// baseline (463.955 us; speedup 1.0000x reference)
//
#include <hip/hip_runtime.h>
#include <cstdint>

// Problem constants (from reference setup_inputs):
//   preds  : (B=16, NC=19, H=512, W=512) float32
//   targets: (B=16, Ht=1024, Wt=1024) int  (labels in [0,19))
//   grid_size g=16 -> Hc=Wc=32 cells, 16384 cells total
// Nearest-neighbor resize: t[b,i,j] = targets[b, 2i, 2j]  (since Ht/H = 2)

#define B_   16
#define NC_  19
#define H_   512
#define W_   512
#define G_   16
#define HC_  32
#define WC_  32
#define NCELL (B_ * HC_ * WC_)            // 16384
#define W4_  (W_ / 4)                     // 128
#define TOTAL4 (B_ * NC_ * H_ * W4_)      // 19,922,944 (fits int)
#define INV_TOTAL (1.0f / (float)((long long)B_ * NC_ * H_ * W_))

// Kernel 1: per-cell class-presence bitmask. One 256-thread block per cell.
__global__ __launch_bounds__(256) void presence_kernel(
    const int* __restrict__ targets,
    uint32_t* __restrict__ masks,
    float* __restrict__ out)
{
    const int cell = blockIdx.x;          // b*1024 + ci*32 + cj
    const int tid  = threadIdx.x;

    // zero the scalar output (harness poisons d_out to 0xAA before each launch)
    if (cell == 0 && tid == 0) out[0] = 0.0f;

    const int cj = cell & 31;
    const int ci = (cell >> 5) & 31;
    const int b  = cell >> 10;

    const int u = tid >> 4;               // 0..15 within-cell row
    const int v = tid & 15;               // 0..15 within-cell col
    const int row = 2 * (ci * G_ + u);    // even rows of targets
    const int col = 2 * (cj * G_ + v);    // even cols of targets

    const int lab = targets[((b << 10) + row) * 1024 + col];
    unsigned m = 1u << lab;

    // wave-wide OR reduction (wave = 64 lanes on gfx950)
    #pragma unroll
    for (int off = 32; off >= 1; off >>= 1)
        m |= __shfl_xor(m, off, 64);

    __shared__ unsigned s_mask;
    if (tid == 0) s_mask = 0u;
    __syncthreads();
    if ((tid & 63) == 0) atomicOr(&s_mask, m);
    __syncthreads();
    if (tid == 0) masks[cell] = s_mask;
}

// Kernel 2: BCE-with-logits mean over preds, se from presence bitmasks.
// loss(x, se) = max(x,0) - se*x + log1p(exp(-|x|))
__global__ __launch_bounds__(256) void bce_kernel(
    const float* __restrict__ preds,
    const uint32_t* __restrict__ masks,
    float* __restrict__ out)
{
    const int tid    = threadIdx.x;
    const int gidx   = blockIdx.x * blockDim.x + tid;
    const int stride = gridDim.x * blockDim.x;

    float acc = 0.0f;

    for (int i4 = gidx; i4 < TOTAL4; i4 += stride) {
        // decode (b, c, row, j4) from flat float4 index; only /19 is non-pow2
        const int j4  = i4 & (W4_ - 1);       // 0..127
        const int t1  = i4 >> 7;
        const int row = t1 & (H_ - 1);        // 0..511
        const int t2  = t1 >> 9;
        const int c   = t2 % NC_;
        const int b   = t2 / NC_;

        // j4*4 .. j4*4+3 share the same 16-wide cell column (4 divides 16)
        const uint32_t m = masks[(b << 10) + ((row >> 4) << 5) + (j4 >> 2)];
        const float se = (float)((m >> c) & 1u);

        const float4 x = ((const float4*)preds)[i4];

        float a, t;
        a = fabsf(x.x); t = __logf(1.0f + __expf(-a));
        acc += fmaxf(x.x, 0.0f) - se * x.x + t;
        a = fabsf(x.y); t = __logf(1.0f + __expf(-a));
        acc += fmaxf(x.y, 0.0f) - se * x.y + t;
        a = fabsf(x.z); t = __logf(1.0f + __expf(-a));
        acc += fmaxf(x.z, 0.0f) - se * x.z + t;
        a = fabsf(x.w); t = __logf(1.0f + __expf(-a));
        acc += fmaxf(x.w, 0.0f) - se * x.w + t;
    }

    // wave reduce
    #pragma unroll
    for (int off = 32; off >= 1; off >>= 1)
        acc += __shfl_down(acc, off, 64);

    __shared__ float s_part[4];           // 256 threads = 4 waves
    const int wave = tid >> 6;
    if ((tid & 63) == 0) s_part[wave] = acc;
    __syncthreads();

    if (tid == 0) {
        float s = s_part[0] + s_part[1] + s_part[2] + s_part[3];
        atomicAdd(out, s * INV_TOTAL);
    }
}

extern "C" void kernel_launch(void* const* d_in, const int* in_sizes, int n_in,
                              void* d_out, int out_size, void* d_ws, size_t ws_size,
                              hipStream_t stream)
{
    const float* preds   = (const float*)d_in[0];
    const int*   targets = (const int*)d_in[1];
    // d_in[2] is grid_size = 16 (compile-time constant G_)

    uint32_t* masks = (uint32_t*)d_ws;    // 16384 * 4 B = 64 KB
    float*    out   = (float*)d_out;

    presence_kernel<<<NCELL, 256, 0, stream>>>(targets, masks, out);

    const int blocks = 4096;              // grid-stride covers TOTAL4
    bce_kernel<<<blocks, 256, 0, stream>>>(preds, masks, out);
}